// Round 2
// baseline (42.465 us; speedup 1.0000x reference)
//
#include <hip/hip_runtime.h>
#include <math.h>

#define NANCH 8400
#define ROWL  37
#define H0    2160
#define W0    3840
#define HW    (H0 * W0)
#define NPART 33

// ws layout (floats): only per-block score partials
#define PART_OFF  40           // NPART*6 floats

typedef float f4 __attribute__((ext_vector_type(4)));

// ---------------------------------------------------------------------------
// K1: per-block partials: max over boxes region, argmax of score under both
// is_norm hypotheses. One anchor per thread (33*256 = 8448 >= 8400).
// ---------------------------------------------------------------------------
__global__ void k_score(const float* __restrict__ pred, float* __restrict__ wsf) {
    int tid = threadIdx.x;
    int t = blockIdx.x * blockDim.x + tid;

    float bmax = -1e30f;
    float vT = -1e30f, vF = -1e30f;
    int   iT = 0, iF = 0;

    if (t < NANCH) {
        const float* row = pred + t * ROWL;
        float cx = row[0], cy = row[1], w = row[2], h = row[3];
        bmax = fmaxf(fmaxf(cx, cy), fmaxf(w, h));

        float l  = row[4];
        float sc = 1.0f / (1.0f + expf(-l));
        float base = fmaxf(sc - 0.5f, 0.0f) + 0.001f;

        float sum = 0.0f;
#pragma unroll
        for (int j = 0; j < 32; ++j) sum += fabsf(row[5 + j]);
        float sb = base * (sum * 0.03125f);   // * maskness (global norm is argmax-invariant)

        float cx6 = cx * 640.0f, cy6 = cy * 640.0f;
        float dxT = fabsf(cx6 - 320.0f) / 320.0f;
        float dyT = fabsf(cy6 - 320.0f) / 320.0f;
        float cwT = fminf(fmaxf(1.0f - 0.5f * (dxT + dyT), 0.0f), 1.0f);
        float dxF = fabsf(cx - 320.0f) / 320.0f;
        float dyF = fabsf(cy - 320.0f) / 320.0f;
        float cwF = fminf(fmaxf(1.0f - 0.5f * (dxF + dyF), 0.0f), 1.0f);

        vT = sb * (0.5f + 0.5f * cwT); iT = t;
        vF = sb * (0.5f + 0.5f * cwF); iF = t;
    }

    __shared__ float sb_[256];
    __shared__ float svT[256]; __shared__ int siT[256];
    __shared__ float svF[256]; __shared__ int siF[256];
    sb_[tid] = bmax;
    svT[tid] = vT; siT[tid] = iT;
    svF[tid] = vF; siF[tid] = iF;
    __syncthreads();

    for (int off = 128; off > 0; off >>= 1) {
        if (tid < off) {
            sb_[tid] = fmaxf(sb_[tid], sb_[tid + off]);
            float ov = svT[tid + off]; int oi = siT[tid + off];
            if (ov > svT[tid] || (ov == svT[tid] && oi < siT[tid])) { svT[tid] = ov; siT[tid] = oi; }
            ov = svF[tid + off]; oi = siF[tid + off];
            if (ov > svF[tid] || (ov == svF[tid] && oi < siF[tid])) { svF[tid] = ov; siF[tid] = oi; }
        }
        __syncthreads();
    }

    if (tid == 0) {
        float* p = wsf + PART_OFF + blockIdx.x * 6;
        int*   q = (int*)p;
        p[0] = sb_[0];
        p[1] = svT[0]; q[2] = siT[0];
        p[3] = svF[0]; q[4] = siF[0];
    }
}

// ---------------------------------------------------------------------------
// sigmoid(bilinear160(logits)) at one 640-grid point, logits = coef . proto.
// Exact same op order as the previous two-stage version (bitwise match).
// ---------------------------------------------------------------------------
__device__ __forceinline__ float sig_eval(int gy, int gx,
                                          const float* __restrict__ proto,
                                          const float* s_coef) {
    float yf = gy * 0.25f - 0.375f;
    int q = (int)floorf(yf); float wy = yf - (float)q;
    float xf = gx * 0.25f - 0.375f;
    int r = (int)floorf(xf); float wx = xf - (float)r;
    int qy0 = max(q, 0), qy1 = min(q + 1, 159);
    int qx0 = max(r, 0), qx1 = min(r + 1, 159);
    int p00 = qy0 * 160 + qx0, p01 = qy0 * 160 + qx1;
    int p10 = qy1 * 160 + qx0, p11 = qy1 * 160 + qx1;
    float a = 0.f, b = 0.f, c = 0.f, d = 0.f;
#pragma unroll
    for (int j = 0; j < 32; ++j) {
        const float* pj = proto + j * 25600;
        float cf = s_coef[j];
        a += cf * pj[p00]; b += cf * pj[p01];
        c += cf * pj[p10]; d += cf * pj[p11];
    }
    float L = (1.0f - wy) * ((1.0f - wx) * a + wx * b)
            +         wy  * ((1.0f - wx) * c + wx * d);
    return 1.0f / (1.0f + expf(-L));
}

// ---------------------------------------------------------------------------
// K2: fused finalize + sigmoid-map + paint.
// Zero-stores issue BEFORE the prologue barrier so the per-block merge
// latency hides under the store stream. Only rect-intersecting quads do the
// on-the-fly mask evaluation (tiny for this data).
// ---------------------------------------------------------------------------
__global__ __launch_bounds__(256, 8) void k_paint_all(const float* __restrict__ x_raw,
                                                      const float* __restrict__ pred,
                                                      const float* __restrict__ proto,
                                                      const float* __restrict__ wsf,
                                                      float* __restrict__ out) {
    int t = blockIdx.x * blockDim.x + threadIdx.x;  // 2160*960 quads
    int Y  = t / 960;
    int xq = t - Y * 960;
    int X0 = xq * 4;
    int pix = Y * W0 + X0;

    // zero pass first — bulk of the store traffic, independent of prologue
    f4 z = {0.f, 0.f, 0.f, 0.f};
    *(f4*)(out + pix)          = z;
    *(f4*)(out + HW + pix)     = z;
    *(f4*)(out + 2 * HW + pix) = z;

    __shared__ float s_fb[4];
    __shared__ float s_coef[32];
    if (threadIdx.x == 0) {
        float bmax = -1e30f;
        float vT = -1e30f, vF = -1e30f;
        int   iT = 0, iF = 0;
        for (int b = 0; b < NPART; ++b) {
            const float* p = wsf + PART_OFF + b * 6;
            const int*   q = (const int*)p;
            bmax = fmaxf(bmax, p[0]);
            if (p[1] > vT || (p[1] == vT && q[2] < iT)) { vT = p[1]; iT = q[2]; }
            if (p[3] > vF || (p[3] == vF && q[4] < iF)) { vF = p[3]; iF = q[4]; }
        }
        int bi = (bmax <= 1.2f) ? iT : iF;
        const float* row = pred + bi * ROWL;
        float cx = row[0], cy = row[1], w = row[2], h = row[3];
        float x1 = fminf(fmaxf(cx - w * 0.5f, 0.0f), 639.0f);
        float y1 = fminf(fmaxf(cy - h * 0.5f, 0.0f), 639.0f);
        float x2 = fminf(fmaxf(cx + w * 0.5f, 0.0f), 639.0f);
        float y2 = fminf(fmaxf(cy + h * 0.5f, 0.0f), 639.0f);
        s_fb[0] = x1 * 6.0f;     // sx = 3840/640
        s_fb[1] = y1 * 3.375f;   // sy = 2160/640
        s_fb[2] = x2 * 6.0f;
        s_fb[3] = y2 * 3.375f;
        for (int j = 0; j < 32; ++j) s_coef[j] = row[5 + j];
    }
    __syncthreads();

    float fbx = s_fb[0], fby = s_fb[1], fbz = s_fb[2], fbw = s_fb[3];
    float ysf = (float)Y;
    if (!((ysf >= fby) && (ysf < fbw))) return;
    if (!(((float)(X0 + 3) >= fbx) && ((float)X0 < fbz))) return;

    // rect-intersecting quad: evaluate mask on the fly
    float yf = (ysf + 0.5f) / 3.375f - 0.5f;
    int   y0 = (int)floorf(yf);
    float wy = yf - (float)y0;
    int y0c = max(y0, 0), y1c = min(y0 + 1, 639);

    float m[4];
    bool any = false;
#pragma unroll
    for (int k = 0; k < 4; ++k) {
        float xs = (float)(X0 + k);
        bool rect = (xs >= fbx) && (xs < fbz);
        m[k] = 0.0f;
        if (rect) {
            float xf = (xs + 0.5f) / 6.0f - 0.5f;
            int   x0 = (int)floorf(xf);
            float wx = xf - (float)x0;
            int x0c = max(x0, 0), x1c = min(x0 + 1, 639);
            float s00 = sig_eval(y0c, x0c, proto, s_coef);
            float s01 = sig_eval(y0c, x1c, proto, s_coef);
            float s10 = sig_eval(y1c, x0c, proto, s_coef);
            float s11 = sig_eval(y1c, x1c, proto, s_coef);
            float v = (1.0f - wy) * ((1.0f - wx) * s00 + wx * s01)
                    +         wy  * ((1.0f - wx) * s10 + wx * s11);
            if (v > 0.72f) { m[k] = 1.0f; any = true; }
        }
    }
    if (!any) return;

    float4 xa = *(const float4*)(x_raw + pix);
    float4 xb = *(const float4*)(x_raw + HW + pix);
    float4 xc = *(const float4*)(x_raw + 2 * HW + pix);
#define CLIP255(v) fminf(fmaxf((v) * 255.0f, 0.0f), 255.0f)
    f4 o0 = {m[0] * CLIP255(xa.x), m[1] * CLIP255(xa.y),
             m[2] * CLIP255(xa.z), m[3] * CLIP255(xa.w)};
    f4 o1 = {m[0] * CLIP255(xb.x), m[1] * CLIP255(xb.y),
             m[2] * CLIP255(xb.z), m[3] * CLIP255(xb.w)};
    f4 o2 = {m[0] * CLIP255(xc.x), m[1] * CLIP255(xc.y),
             m[2] * CLIP255(xc.z), m[3] * CLIP255(xc.w)};
#undef CLIP255
    *(f4*)(out + pix)          = o0;
    *(f4*)(out + HW + pix)     = o1;
    *(f4*)(out + 2 * HW + pix) = o2;
}

// ---------------------------------------------------------------------------
extern "C" void kernel_launch(void* const* d_in, const int* in_sizes, int n_in,
                              void* d_out, int out_size, void* d_ws, size_t ws_size,
                              hipStream_t stream) {
    const float* x_raw = (const float*)d_in[0];
    const float* pred  = (const float*)d_in[1];
    const float* proto = (const float*)d_in[2];
    float* out = (float*)d_out;
    float* wsf = (float*)d_ws;

    k_score    <<<dim3(NPART), dim3(256), 0, stream>>>(pred, wsf);
    k_paint_all<<<dim3(8100),  dim3(256), 0, stream>>>(x_raw, pred, proto, wsf, out);
}

// Round 3
// 31.754 us; speedup vs baseline: 1.3373x; 1.3373x over previous
//
#include <hip/hip_runtime.h>
#include <math.h>

#define NANCH 8400
#define ROWL  37
#define H0    2160
#define W0    3840
#define HW    (H0 * W0)
#define NPART 33

// ws layout (floats): per-block score partials only
#define PART_OFF  40           // NPART*6 floats

typedef float f4 __attribute__((ext_vector_type(4)));

// ---------------------------------------------------------------------------
// K1: zero the whole output (store-BW bound, ~97 MB). Blocks 0..32 also run
// the score reduction — hidden under the store stream. No barrier interacts
// with the store path for the other 8067 blocks.
// pix = 4*t identity: Y = t/960, X0 = 4*(t%960) -> Y*3840 + X0 = 4t.
// ---------------------------------------------------------------------------
__global__ __launch_bounds__(256) void k_zero_score(const float* __restrict__ pred,
                                                    float* __restrict__ wsf,
                                                    float* __restrict__ out) {
    int tid = threadIdx.x;
    int t = blockIdx.x * 256 + tid;
    int pix = t * 4;

    f4 z = {0.f, 0.f, 0.f, 0.f};
    *(f4*)(out + pix)          = z;
    *(f4*)(out + HW + pix)     = z;
    *(f4*)(out + 2 * HW + pix) = z;

    if (blockIdx.x >= NPART) return;

    // ---- score phase (blocks 0..32 only; identical math to round-1) ----
    int a = blockIdx.x * 256 + tid;

    float bmax = -1e30f;
    float vT = -1e30f, vF = -1e30f;
    int   iT = 0, iF = 0;

    if (a < NANCH) {
        const float* row = pred + a * ROWL;
        float cx = row[0], cy = row[1], w = row[2], h = row[3];
        bmax = fmaxf(fmaxf(cx, cy), fmaxf(w, h));

        float l  = row[4];
        float sc = 1.0f / (1.0f + expf(-l));
        float base = fmaxf(sc - 0.5f, 0.0f) + 0.001f;

        float sum = 0.0f;
#pragma unroll
        for (int j = 0; j < 32; ++j) sum += fabsf(row[5 + j]);
        float sb = base * (sum * 0.03125f);   // global maskness norm is argmax-invariant

        float cx6 = cx * 640.0f, cy6 = cy * 640.0f;
        float dxT = fabsf(cx6 - 320.0f) / 320.0f;
        float dyT = fabsf(cy6 - 320.0f) / 320.0f;
        float cwT = fminf(fmaxf(1.0f - 0.5f * (dxT + dyT), 0.0f), 1.0f);
        float dxF = fabsf(cx - 320.0f) / 320.0f;
        float dyF = fabsf(cy - 320.0f) / 320.0f;
        float cwF = fminf(fmaxf(1.0f - 0.5f * (dxF + dyF), 0.0f), 1.0f);

        vT = sb * (0.5f + 0.5f * cwT); iT = a;
        vF = sb * (0.5f + 0.5f * cwF); iF = a;
    }

    __shared__ float sb_[256];
    __shared__ float svT[256]; __shared__ int siT[256];
    __shared__ float svF[256]; __shared__ int siF[256];
    sb_[tid] = bmax;
    svT[tid] = vT; siT[tid] = iT;
    svF[tid] = vF; siF[tid] = iF;
    __syncthreads();

    for (int off = 128; off > 0; off >>= 1) {
        if (tid < off) {
            sb_[tid] = fmaxf(sb_[tid], sb_[tid + off]);
            float ov = svT[tid + off]; int oi = siT[tid + off];
            if (ov > svT[tid] || (ov == svT[tid] && oi < siT[tid])) { svT[tid] = ov; siT[tid] = oi; }
            ov = svF[tid + off]; oi = siF[tid + off];
            if (ov > svF[tid] || (ov == svF[tid] && oi < siF[tid])) { svF[tid] = ov; siF[tid] = oi; }
        }
        __syncthreads();
    }

    if (tid == 0) {
        float* p = wsf + PART_OFF + blockIdx.x * 6;
        int*   q = (int*)p;
        p[0] = sb_[0];
        p[1] = svT[0]; q[2] = siT[0];
        p[3] = svF[0]; q[4] = siF[0];
    }
}

// ---------------------------------------------------------------------------
// sigmoid(bilinear160(coef . proto)) at one 640-grid point. Same op order as
// the round-1 two-stage version (bitwise match).
// ---------------------------------------------------------------------------
__device__ __forceinline__ float sig_eval(int gy, int gx,
                                          const float* __restrict__ proto,
                                          const float* c) {
    float yf = gy * 0.25f - 0.375f;
    int q = (int)floorf(yf); float wy = yf - (float)q;
    float xf = gx * 0.25f - 0.375f;
    int r = (int)floorf(xf); float wx = xf - (float)r;
    int qy0 = max(q, 0), qy1 = min(q + 1, 159);
    int qx0 = max(r, 0), qx1 = min(r + 1, 159);
    int p00 = qy0 * 160 + qx0, p01 = qy0 * 160 + qx1;
    int p10 = qy1 * 160 + qx0, p11 = qy1 * 160 + qx1;
    float a = 0.f, b = 0.f, cc = 0.f, d = 0.f;
#pragma unroll
    for (int j = 0; j < 32; ++j) {
        const float* pj = proto + j * 25600;
        float cf = c[j];
        a  += cf * pj[p00]; b += cf * pj[p01];
        cc += cf * pj[p10]; d += cf * pj[p11];
    }
    float L = (1.0f - wy) * ((1.0f - wx) * a + wx * b)
            +         wy  * ((1.0f - wx) * cc + wx * d);
    return 1.0f / (1.0f + expf(-L));
}

// ---------------------------------------------------------------------------
// K2: per-wave in-register merge of the 33 partials (no LDS, no barrier),
// rect test, early exit. In-rect quads evaluate the mask on the fly and
// overwrite their zeros.
// ---------------------------------------------------------------------------
__global__ __launch_bounds__(256) void k_rect_paint(const float* __restrict__ x_raw,
                                                    const float* __restrict__ pred,
                                                    const float* __restrict__ proto,
                                                    const float* __restrict__ wsf,
                                                    float* __restrict__ out) {
    int tid  = threadIdx.x;
    int t    = blockIdx.x * 256 + tid;
    int lane = tid & 63;

    // ---- wave-level merge of partials ----
    float bmax = -1e30f, vT = -1e30f, vF = -1e30f;
    int   iT = 0x7fffffff, iF = 0x7fffffff;
    if (lane < NPART) {
        const float* p = wsf + PART_OFF + lane * 6;
        const int*   q = (const int*)p;
        bmax = p[0];
        vT = p[1]; iT = q[2];
        vF = p[3]; iF = q[4];
    }
#pragma unroll
    for (int off = 1; off < 64; off <<= 1) {
        bmax = fmaxf(bmax, __shfl_xor(bmax, off));
        float ov = __shfl_xor(vT, off); int oi = __shfl_xor(iT, off);
        if (ov > vT || (ov == vT && oi < iT)) { vT = ov; iT = oi; }
        ov = __shfl_xor(vF, off); oi = __shfl_xor(iF, off);
        if (ov > vF || (ov == vF && oi < iF)) { vF = ov; iF = oi; }
    }
    int bi = (bmax <= 1.2f) ? iT : iF;   // wave-uniform

    const float* row = pred + bi * ROWL;
    float cx = row[0], cy = row[1], w = row[2], h = row[3];
    float x1 = fminf(fmaxf(cx - w * 0.5f, 0.0f), 639.0f);
    float y1 = fminf(fmaxf(cy - h * 0.5f, 0.0f), 639.0f);
    float x2 = fminf(fmaxf(cx + w * 0.5f, 0.0f), 639.0f);
    float y2 = fminf(fmaxf(cy + h * 0.5f, 0.0f), 639.0f);
    float fbx = x1 * 6.0f;      // sx = 3840/640
    float fby = y1 * 3.375f;    // sy = 2160/640
    float fbz = x2 * 6.0f;
    float fbw = y2 * 3.375f;

    int Y  = t / 960;
    int X0 = (t - Y * 960) * 4;
    int pix = t * 4;

    float ysf = (float)Y;
    if (!((ysf >= fby) && (ysf < fbw))) return;
    if (!(((float)(X0 + 3) >= fbx) && ((float)X0 < fbz))) return;

    // ---- in-rect: evaluate mask on the fly ----
    float c[32];
#pragma unroll
    for (int j = 0; j < 32; ++j) c[j] = row[5 + j];

    float yf = (ysf + 0.5f) / 3.375f - 0.5f;
    int   y0 = (int)floorf(yf);
    float wy = yf - (float)y0;
    int y0c = max(y0, 0), y1c = min(y0 + 1, 639);

    float m[4];
    bool any = false;
#pragma unroll
    for (int k = 0; k < 4; ++k) {
        float xs = (float)(X0 + k);
        bool rect = (xs >= fbx) && (xs < fbz);
        m[k] = 0.0f;
        if (rect) {
            float xf = (xs + 0.5f) / 6.0f - 0.5f;
            int   x0 = (int)floorf(xf);
            float wx = xf - (float)x0;
            int x0c = max(x0, 0), x1c = min(x0 + 1, 639);
            float s00 = sig_eval(y0c, x0c, proto, c);
            float s01 = sig_eval(y0c, x1c, proto, c);
            float s10 = sig_eval(y1c, x0c, proto, c);
            float s11 = sig_eval(y1c, x1c, proto, c);
            float v = (1.0f - wy) * ((1.0f - wx) * s00 + wx * s01)
                    +         wy  * ((1.0f - wx) * s10 + wx * s11);
            if (v > 0.72f) { m[k] = 1.0f; any = true; }
        }
    }
    if (!any) return;

    float4 xa = *(const float4*)(x_raw + pix);
    float4 xb = *(const float4*)(x_raw + HW + pix);
    float4 xc = *(const float4*)(x_raw + 2 * HW + pix);
#define CLIP255(v) fminf(fmaxf((v) * 255.0f, 0.0f), 255.0f)
    f4 o0 = {m[0] * CLIP255(xa.x), m[1] * CLIP255(xa.y),
             m[2] * CLIP255(xa.z), m[3] * CLIP255(xa.w)};
    f4 o1 = {m[0] * CLIP255(xb.x), m[1] * CLIP255(xb.y),
             m[2] * CLIP255(xb.z), m[3] * CLIP255(xb.w)};
    f4 o2 = {m[0] * CLIP255(xc.x), m[1] * CLIP255(xc.y),
             m[2] * CLIP255(xc.z), m[3] * CLIP255(xc.w)};
#undef CLIP255
    *(f4*)(out + pix)          = o0;
    *(f4*)(out + HW + pix)     = o1;
    *(f4*)(out + 2 * HW + pix) = o2;
}

// ---------------------------------------------------------------------------
extern "C" void kernel_launch(void* const* d_in, const int* in_sizes, int n_in,
                              void* d_out, int out_size, void* d_ws, size_t ws_size,
                              hipStream_t stream) {
    const float* x_raw = (const float*)d_in[0];
    const float* pred  = (const float*)d_in[1];
    const float* proto = (const float*)d_in[2];
    float* out = (float*)d_out;
    float* wsf = (float*)d_ws;

    k_zero_score<<<dim3(8100), dim3(256), 0, stream>>>(pred, wsf, out);
    k_rect_paint<<<dim3(8100), dim3(256), 0, stream>>>(x_raw, pred, proto, wsf, out);
}

// Round 4
// 27.209 us; speedup vs baseline: 1.5607x; 1.1670x over previous
//
#include <hip/hip_runtime.h>
#include <math.h>

#define NANCH 8400
#define ROWL  37
#define H0    2160
#define W0    3840
#define HW    (H0 * W0)
#define NPART 33

// ws layout (floats): per-block score partials only
#define PART_OFF  40           // NPART*6 floats

typedef float f4 __attribute__((ext_vector_type(4)));

// ---------------------------------------------------------------------------
// K1: score reduction only. 33 blocks x 256 threads, one anchor per thread.
// Per-block partials: box-max, argmax under both is_norm hypotheses.
// ---------------------------------------------------------------------------
__global__ __launch_bounds__(256) void k_score(const float* __restrict__ pred,
                                               float* __restrict__ wsf) {
    int tid = threadIdx.x;
    int a = blockIdx.x * 256 + tid;

    float bmax = -1e30f;
    float vT = -1e30f, vF = -1e30f;
    int   iT = 0, iF = 0;

    if (a < NANCH) {
        const float* row = pred + a * ROWL;
        float cx = row[0], cy = row[1], w = row[2], h = row[3];
        bmax = fmaxf(fmaxf(cx, cy), fmaxf(w, h));

        float l  = row[4];
        float sc = 1.0f / (1.0f + expf(-l));
        float base = fmaxf(sc - 0.5f, 0.0f) + 0.001f;

        float sum = 0.0f;
#pragma unroll
        for (int j = 0; j < 32; ++j) sum += fabsf(row[5 + j]);
        float sb = base * (sum * 0.03125f);   // global maskness norm is argmax-invariant

        float cx6 = cx * 640.0f, cy6 = cy * 640.0f;
        float dxT = fabsf(cx6 - 320.0f) / 320.0f;
        float dyT = fabsf(cy6 - 320.0f) / 320.0f;
        float cwT = fminf(fmaxf(1.0f - 0.5f * (dxT + dyT), 0.0f), 1.0f);
        float dxF = fabsf(cx - 320.0f) / 320.0f;
        float dyF = fabsf(cy - 320.0f) / 320.0f;
        float cwF = fminf(fmaxf(1.0f - 0.5f * (dxF + dyF), 0.0f), 1.0f);

        vT = sb * (0.5f + 0.5f * cwT); iT = a;
        vF = sb * (0.5f + 0.5f * cwF); iF = a;
    }

    __shared__ float sb_[256];
    __shared__ float svT[256]; __shared__ int siT[256];
    __shared__ float svF[256]; __shared__ int siF[256];
    sb_[tid] = bmax;
    svT[tid] = vT; siT[tid] = iT;
    svF[tid] = vF; siF[tid] = iF;
    __syncthreads();

    for (int off = 128; off > 0; off >>= 1) {
        if (tid < off) {
            sb_[tid] = fmaxf(sb_[tid], sb_[tid + off]);
            float ov = svT[tid + off]; int oi = siT[tid + off];
            if (ov > svT[tid] || (ov == svT[tid] && oi < siT[tid])) { svT[tid] = ov; siT[tid] = oi; }
            ov = svF[tid + off]; oi = siF[tid + off];
            if (ov > svF[tid] || (ov == svF[tid] && oi < siF[tid])) { svF[tid] = ov; siF[tid] = oi; }
        }
        __syncthreads();
    }

    if (tid == 0) {
        float* p = wsf + PART_OFF + blockIdx.x * 6;
        int*   q = (int*)p;
        p[0] = sb_[0];
        p[1] = svT[0]; q[2] = siT[0];
        p[3] = svF[0]; q[4] = siF[0];
    }
}

// ---------------------------------------------------------------------------
// sigmoid(bilinear160(coef . proto)) at one 640-grid point. Same op order as
// the round-1 two-stage version (bitwise match).
// ---------------------------------------------------------------------------
__device__ __forceinline__ float sig_eval(int gy, int gx,
                                          const float* __restrict__ proto,
                                          const float* c) {
    float yf = gy * 0.25f - 0.375f;
    int q = (int)floorf(yf); float wy = yf - (float)q;
    float xf = gx * 0.25f - 0.375f;
    int r = (int)floorf(xf); float wx = xf - (float)r;
    int qy0 = max(q, 0), qy1 = min(q + 1, 159);
    int qx0 = max(r, 0), qx1 = min(r + 1, 159);
    int p00 = qy0 * 160 + qx0, p01 = qy0 * 160 + qx1;
    int p10 = qy1 * 160 + qx0, p11 = qy1 * 160 + qx1;
    float a = 0.f, b = 0.f, cc = 0.f, d = 0.f;
#pragma unroll
    for (int j = 0; j < 32; ++j) {
        const float* pj = proto + j * 25600;
        float cf = c[j];
        a  += cf * pj[p00]; b += cf * pj[p01];
        cc += cf * pj[p10]; d += cf * pj[p11];
    }
    float L = (1.0f - wy) * ((1.0f - wx) * a + wx * b)
            +         wy  * ((1.0f - wx) * cc + wx * d);
    return 1.0f / (1.0f + expf(-L));
}

// ---------------------------------------------------------------------------
// K2: single output sweep. Per-wave in-register merge of the 33 partials
// (no LDS, no barrier), then each thread stores zeros or masked pixels for
// its 4-pixel quad. Out-of-rect threads never read x_raw.
// ---------------------------------------------------------------------------
__global__ __launch_bounds__(256) void k_paint(const float* __restrict__ x_raw,
                                               const float* __restrict__ pred,
                                               const float* __restrict__ proto,
                                               const float* __restrict__ wsf,
                                               float* __restrict__ out) {
    int tid  = threadIdx.x;
    int t    = blockIdx.x * 256 + tid;
    int lane = tid & 63;

    // ---- wave-level merge of partials (L2-hot 800 B) ----
    float bmax = -1e30f, vT = -1e30f, vF = -1e30f;
    int   iT = 0x7fffffff, iF = 0x7fffffff;
    if (lane < NPART) {
        const float* p = wsf + PART_OFF + lane * 6;
        const int*   q = (const int*)p;
        bmax = p[0];
        vT = p[1]; iT = q[2];
        vF = p[3]; iF = q[4];
    }
#pragma unroll
    for (int off = 1; off < 64; off <<= 1) {
        bmax = fmaxf(bmax, __shfl_xor(bmax, off));
        float ov = __shfl_xor(vT, off); int oi = __shfl_xor(iT, off);
        if (ov > vT || (ov == vT && oi < iT)) { vT = ov; iT = oi; }
        ov = __shfl_xor(vF, off); oi = __shfl_xor(iF, off);
        if (ov > vF || (ov == vF && oi < iF)) { vF = ov; iF = oi; }
    }
    int bi = (bmax <= 1.2f) ? iT : iF;   // wave-uniform

    const float* row = pred + bi * ROWL;
    float cx = row[0], cy = row[1], w = row[2], h = row[3];
    float x1 = fminf(fmaxf(cx - w * 0.5f, 0.0f), 639.0f);
    float y1 = fminf(fmaxf(cy - h * 0.5f, 0.0f), 639.0f);
    float x2 = fminf(fmaxf(cx + w * 0.5f, 0.0f), 639.0f);
    float y2 = fminf(fmaxf(cy + h * 0.5f, 0.0f), 639.0f);
    float fbx = x1 * 6.0f;      // sx = 3840/640
    float fby = y1 * 3.375f;    // sy = 2160/640
    float fbz = x2 * 6.0f;
    float fbw = y2 * 3.375f;

    int Y  = t / 960;
    int X0 = (t - Y * 960) * 4;
    int pix = t * 4;            // == Y*3840 + X0

    float ysf = (float)Y;
    bool inrect = (ysf >= fby) && (ysf < fbw)
               && ((float)(X0 + 3) >= fbx) && ((float)X0 < fbz);

    f4 o0 = {0.f, 0.f, 0.f, 0.f};
    f4 o1 = o0, o2 = o0;

    if (inrect) {
        // coef for the winning anchor (wave-uniform row, scalar loads)
        float c[32];
#pragma unroll
        for (int j = 0; j < 32; ++j) c[j] = row[5 + j];

        float yf = (ysf + 0.5f) / 3.375f - 0.5f;
        int   y0 = (int)floorf(yf);
        float wy = yf - (float)y0;
        int y0c = max(y0, 0), y1c = min(y0 + 1, 639);

        float m[4];
        bool any = false;
#pragma unroll
        for (int k = 0; k < 4; ++k) {
            float xs = (float)(X0 + k);
            bool rect = (xs >= fbx) && (xs < fbz);
            m[k] = 0.0f;
            if (rect) {
                float xf = (xs + 0.5f) / 6.0f - 0.5f;
                int   x0 = (int)floorf(xf);
                float wx = xf - (float)x0;
                int x0c = max(x0, 0), x1c = min(x0 + 1, 639);
                float s00 = sig_eval(y0c, x0c, proto, c);
                float s01 = sig_eval(y0c, x1c, proto, c);
                float s10 = sig_eval(y1c, x0c, proto, c);
                float s11 = sig_eval(y1c, x1c, proto, c);
                float v = (1.0f - wy) * ((1.0f - wx) * s00 + wx * s01)
                        +         wy  * ((1.0f - wx) * s10 + wx * s11);
                if (v > 0.72f) { m[k] = 1.0f; any = true; }
            }
        }
        if (any) {
            float4 xa = *(const float4*)(x_raw + pix);
            float4 xb = *(const float4*)(x_raw + HW + pix);
            float4 xc = *(const float4*)(x_raw + 2 * HW + pix);
#define CLIP255(v) fminf(fmaxf((v) * 255.0f, 0.0f), 255.0f)
            o0 = (f4){m[0] * CLIP255(xa.x), m[1] * CLIP255(xa.y),
                      m[2] * CLIP255(xa.z), m[3] * CLIP255(xa.w)};
            o1 = (f4){m[0] * CLIP255(xb.x), m[1] * CLIP255(xb.y),
                      m[2] * CLIP255(xb.z), m[3] * CLIP255(xb.w)};
            o2 = (f4){m[0] * CLIP255(xc.x), m[1] * CLIP255(xc.y),
                      m[2] * CLIP255(xc.z), m[3] * CLIP255(xc.w)};
#undef CLIP255
        }
    }

    *(f4*)(out + pix)          = o0;
    *(f4*)(out + HW + pix)     = o1;
    *(f4*)(out + 2 * HW + pix) = o2;
}

// ---------------------------------------------------------------------------
extern "C" void kernel_launch(void* const* d_in, const int* in_sizes, int n_in,
                              void* d_out, int out_size, void* d_ws, size_t ws_size,
                              hipStream_t stream) {
    const float* x_raw = (const float*)d_in[0];
    const float* pred  = (const float*)d_in[1];
    const float* proto = (const float*)d_in[2];
    float* out = (float*)d_out;
    float* wsf = (float*)d_ws;

    k_score<<<dim3(NPART), dim3(256), 0, stream>>>(pred, wsf);
    k_paint<<<dim3(8100),  dim3(256), 0, stream>>>(x_raw, pred, proto, wsf, out);
}